// Round 7
// baseline (292.481 us; speedup 1.0000x reference)
//
#include <hip/hip_runtime.h>
#include <stdint.h>

#define NA 200000
#define NB 8
#define NM 64
#define APB 1024                // anchors per k_main block (4 per thread)
#define CPB 196                 // 196*1024 = 200704 >= 200000
#define NA4 50000               // NA/4 uint4 per image (fallback scans)
#define CAP 8192                // per-image candidate bucket capacity

// ---- workspace layout (dword offsets) ----
// scal: 8 images x 16 slots: [0]np [1]nn [2]ps(f32) [3]bs(f32) [5]bucket_count
#define O_SCAL 0
#define O_L1C  128                   // 8 x 256 counts
#define O_L1S  2176                  // 8 x 256 sums
#define O_KEYS 4224                  // 8 x 200000 keys (16B-aligned)
#define O_BKT  (O_KEYS + NB*NA)      // 8 x 8192 candidate keys (>= 2.0)
#define N_ZERO 4224                  // zero scal + L1 hist only (16.9 KB)

__device__ __forceinline__ unsigned int f2key(float f) {
    unsigned int u = __float_as_uint(f);
    return (u & 0x80000000u) ? ~u : (u | 0x80000000u);
}
__device__ __forceinline__ float key2f(unsigned int k) {
    return (k & 0x80000000u) ? __uint_as_float(k & 0x7fffffffu) : __uint_as_float(~k);
}

// per-anchor epilogue: key write + LDS L1 hist + pos-path box loss. Returns key.
__device__ __forceinline__ unsigned int epi(
    int b, int i, float4 a4, int arg, bool pos, bool neg,
    const float* __restrict__ cls, const float* __restrict__ reg,
    const float4* sbox, unsigned int* __restrict__ keys,
    unsigned int* hc8, float* hs8, float& posv, float& boxv)
{
    const float2 cv = ((const float2*)cls)[(size_t)b * NA + i];
    unsigned int key = 0u;   // excluded anchors: key 0 (< any real key >= 0x00800000)
    if (neg) {
        const float nl = -cv.y;
        key = f2key(nl);
        atomicAdd(&hc8[key >> 24], 1u);
        atomicAdd(&hs8[key >> 24], nl);
    }
    keys[(size_t)b * NA + i] = key;
    if (pos) {
        posv += -cv.x;
        const float4 g = sbox[arg];
        const float aw = a4.z - a4.x, ah = a4.w - a4.y;
        const float acx = a4.x + 0.5f * aw, acy = a4.y + 0.5f * ah;
        const float gw = g.z - g.x, gh = g.w - g.y;
        const float gcx = g.x + 0.5f * gw, gcy = g.y + 0.5f * gh;
        const float t0 = ((gcx - acx) / (aw + 1e-14f)) / 0.1f;
        const float t1 = ((gcy - acy) / (ah + 1e-14f)) / 0.1f;
        const float t2 = logf(gw / aw) / 0.2f;
        const float t3 = logf(gh / ah) / 0.2f;
        const float4 r = ((const float4*)reg)[(size_t)b * NA + i];
        const float d0 = fabsf(t0 - r.x);
        const float d1 = fabsf(t1 - r.y);
        const float d2 = fabsf(t2 - r.z);
        const float d3 = fabsf(t3 - r.w);
        const float l0 = (d0 < 1.0f) ? 0.5f * d0 * d0 : d0 - 0.5f;
        const float l1 = (d1 < 1.0f) ? 0.5f * d1 * d1 : d1 - 0.5f;
        const float l2 = (d2 < 1.0f) ? 0.5f * d2 * d2 : d2 - 0.5f;
        const float l3 = (d3 < 1.0f) ? 0.5f * d3 * d3 : d3 - 0.5f;
        boxv += l0 + l1 + l2 + l3;
    }
    return key;
}

// wave-aggregated bucket append for keys >= 2.0 (key >= 0xC0000000).
// Must be called in wave-uniform control flow.
__device__ __forceinline__ void bkt_append(unsigned int key, unsigned int* cnt_gl,
                                           unsigned int* __restrict__ bkt)
{
    const unsigned long long m = __ballot(key >= 0xC0000000u);
    if (!m) return;
    const int lane = (int)(threadIdx.x & 63u);
    const int leader = __ffsll((long long)m) - 1;
    unsigned int base = 0u;
    if (lane == leader) base = atomicAdd(cnt_gl, (unsigned int)__popcll(m));
    base = __shfl(base, leader);
    if (key >= 0xC0000000u) {
        const unsigned int off = base + (unsigned int)__popcll(m & ((1ull << lane) - 1ull));
        if (off < CAP) bkt[off] = key;   // clamp: overflow -> fallback path used anyway
    }
}

// ---------------- K1: IoU argmax (cross-multiply), 4 anchors/thread, 4-box register stages ----
__global__ __launch_bounds__(256, 4) void k_main(
    const float* __restrict__ cls, const float* __restrict__ reg,
    const float* __restrict__ anchors, const float* __restrict__ ann,
    unsigned int* __restrict__ scal, unsigned int* __restrict__ l1cnt,
    float* __restrict__ l1sum, unsigned int* __restrict__ keys,
    unsigned int* __restrict__ bkt)
{
    __shared__ float4 sbox[NM];
    __shared__ unsigned int hc8[256];
    __shared__ float hs8[256];
    __shared__ unsigned int s_np, s_nn;
    __shared__ float s_ps, s_bs;

    const int b = blockIdx.y;
    const int tid = threadIdx.x;
    if (tid < NM) {
        float4 bb = ((const float4*)ann)[b * NM + tid];
        if (!(bb.x > 0.0f)) {   // invalid -> inter 0, ua inf, ratio 0 (bit-exact vs ref, r3-r6)
            bb.x = __builtin_inff(); bb.y = __builtin_inff();
            bb.z = -__builtin_inff(); bb.w = -__builtin_inff();
        }
        sbox[tid] = bb;
    }
    hc8[tid] = 0u; hs8[tid] = 0.0f;
    if (tid == 0) { s_np = 0u; s_nn = 0u; s_ps = 0.0f; s_bs = 0.0f; }
    __syncthreads();

    const int i0 = blockIdx.x * APB + tid;
    float4 A[4];
#pragma unroll
    for (int t = 0; t < 4; ++t) {
        const int it = i0 + 256 * t;
        A[t] = make_float4(0.f, 0.f, 0.f, 0.f);
        if (it < NA) A[t] = ((const float4*)anchors)[it];
    }

    float bi[4] = {-1.f, -1.f, -1.f, -1.f};
    float bu[4] = {1.f, 1.f, 1.f, 1.f};
    int arg[4] = {0, 0, 0, 0};
    bool pos[4], neg[4];
    {
#pragma clang fp contract(off)
        float aa[4];
#pragma unroll
        for (int t = 0; t < 4; ++t) aa[t] = (A[t].z - A[t].x) * (A[t].w - A[t].y);
#pragma unroll 1
        for (int mo = 0; mo < NM; mo += 4) {
            float4 bb[4]; float ab[4];
#pragma unroll
            for (int j = 0; j < 4; ++j) {
                bb[j] = sbox[mo + j];                              // ds_read_b128, held in regs
                ab[j] = (bb[j].z - bb[j].x) * (bb[j].w - bb[j].y);
            }
#pragma unroll
            for (int j = 0; j < 4; ++j) {
#pragma unroll
                for (int t = 0; t < 4; ++t) {
                    const float iw = fmaxf(fminf(A[t].z, bb[j].z) - fmaxf(A[t].x, bb[j].x), 0.0f);
                    const float ih = fmaxf(fminf(A[t].w, bb[j].w) - fmaxf(A[t].y, bb[j].y), 0.0f);
                    const float inter = iw * ih;
                    const float ua = fmaxf(aa[t] + ab[j] - inter, 1e-8f);
                    if (inter * bu[t] > bi[t] * ua) { bi[t] = inter; bu[t] = ua; arg[t] = mo + j; }
                }
            }
        }
#pragma unroll
        for (int t = 0; t < 4; ++t) {
            pos[t] = (bi[t] >= 0.5f * bu[t]);
            neg[t] = (bi[t] <  0.3f * bu[t]);
        }
    }

    float posv = 0.0f, boxv = 0.0f;
    unsigned int key[4] = {0u, 0u, 0u, 0u};
#pragma unroll
    for (int t = 0; t < 4; ++t) {
        const int it = i0 + 256 * t;
        if (it < NA) {
            key[t] = epi(b, it, A[t], arg[t], pos[t], neg[t], cls, reg,
                         (const float4*)sbox, keys, hc8, hs8, posv, boxv);
        } else { pos[t] = false; neg[t] = false; }
    }

    // candidate bucket (keys >= 2.0): wave-aggregated append (uniform control flow here)
    unsigned int* bcnt = scal + b * 16 + 5;
    unsigned int* bb_gl = bkt + b * CAP;
#pragma unroll
    for (int t = 0; t < 4; ++t) bkt_append(key[t], bcnt, bb_gl);

    // wave -> block -> one global flush per block
    unsigned int pc = 0, nc = 0;
    unsigned long long anypos = 0ull;
#pragma unroll
    for (int t = 0; t < 4; ++t) {
        const unsigned long long pb = __ballot(pos[t]);
        const unsigned long long nb = __ballot(neg[t]);
        anypos |= pb;
        pc += (unsigned int)__popcll(pb);
        nc += (unsigned int)__popcll(nb);
    }
    if (anypos) {
        for (int off = 32; off; off >>= 1) {
            posv += __shfl_xor(posv, off);
            boxv += __shfl_xor(boxv, off);
        }
    }
    if ((tid & 63) == 0) {
        if (nc) atomicAdd(&s_nn, nc);
        if (pc) { atomicAdd(&s_np, pc); atomicAdd(&s_ps, posv); atomicAdd(&s_bs, boxv); }
    }
    __syncthreads();
    unsigned int* sg = scal + b * 16;
    if (tid == 0) {
        if (s_nn) atomicAdd(&sg[1], s_nn);
        if (s_np) {
            atomicAdd(&sg[0], s_np);
            atomicAdd((float*)(sg + 2), s_ps);
            atomicAdd((float*)(sg + 3), s_bs);
        }
    }
    if (hc8[tid]) {
        atomicAdd(&l1cnt[b * 256 + tid], hc8[tid]);
        atomicAdd(&l1sum[b * 256 + tid], hs8[tid]);
    }
}

// select over 4096-bin LDS histogram; 1024-thread block, threads <256 active. (fallback path)
__device__ void sel4096_lds(const unsigned int* hc, const float* hs, unsigned int target,
                            unsigned int* s_sc, float* s_ss, unsigned int* s_res, float* s_resf,
                            unsigned int* c, unsigned int* cab, float* sab)
{
    const int t = threadIdx.x;
    unsigned int cb[16]; float sb[16];
    if (t < 256) {
        unsigned int cc = 0; float cs = 0.0f;
#pragma unroll
        for (int j = 0; j < 16; ++j) {
            cb[j] = hc[t * 16 + j]; sb[j] = hs[t * 16 + j];
            cc += cb[j]; cs += sb[j];
        }
        s_sc[t] = cc; s_ss[t] = cs;
    }
    __syncthreads();
    for (int d = 1; d < 256; d <<= 1) {
        unsigned int uc = 0; float fs = 0.0f;
        if (t < 256) { uc = (t + d < 256) ? s_sc[t + d] : 0u; fs = (t + d < 256) ? s_ss[t + d] : 0.0f; }
        __syncthreads();
        if (t < 256) { s_sc[t] += uc; s_ss[t] += fs; }
        __syncthreads();
    }
    if (t < 256) {
        unsigned int run = (t < 255) ? s_sc[t + 1] : 0u;
        float runs = (t < 255) ? s_ss[t + 1] : 0.0f;
#pragma unroll
        for (int j = 15; j >= 0; --j) {
            const unsigned int prev = run; const float prevs = runs;
            run += cb[j]; runs += sb[j];
            if (run >= target && prev < target) {
                s_res[0] = (unsigned int)(t * 16 + j); s_res[1] = prev; *s_resf = prevs;
            }
        }
    }
    __syncthreads();
    *c = s_res[0]; *cab = s_res[1]; *sab = *s_resf;
    __syncthreads();
}

// ---------------- K2: top-k sum. FAST: in-LDS 4-level radix over candidate bucket.
//                  FALLBACK (k > bucket or overflow): r6 global-scan path. ----------------
__global__ __launch_bounds__(1024) void k_tail(
    const unsigned int* __restrict__ keys, const unsigned int* __restrict__ scal,
    const unsigned int* __restrict__ l1c, const float* __restrict__ l1s,
    const unsigned int* __restrict__ bkt, float* __restrict__ out)
{
    __shared__ unsigned int big[8192];   // fast: candidates | fallback: hc[0..4095]+hs[4096..8191]
    __shared__ unsigned int hcnt[256];
    __shared__ float hsum[256];
    __shared__ unsigned int s_sc[256];
    __shared__ float s_ss[256];
    __shared__ unsigned int s_res[2];
    __shared__ float s_resf;

    const int b = blockIdx.x;
    const int tid = threadIdx.x;
    const unsigned int np = scal[b * 16], nn = scal[b * 16 + 1], bc = scal[b * 16 + 5];
    unsigned int k = 0;
    if (np) { const unsigned int kp = np * 3u; k = (kp < nn) ? kp : nn; }
    float s_top = 0.0f;

    if (k > 0 && k <= bc && bc <= CAP) {
        // ---- FAST PATH: all top-k candidates (and threshold) are in the bucket ----
        for (unsigned int j = tid; j < bc; j += 1024) big[j] = bkt[b * CAP + j];
        __syncthreads();
        unsigned int prefix = 0u, target = k;
        float sumab = 0.0f;
#pragma unroll 1
        for (int lv = 0; lv < 4; ++lv) {
            const int sh = 24 - 8 * lv;
            if (tid < 256) { hcnt[tid] = 0u; hsum[tid] = 0.0f; }
            __syncthreads();
            for (unsigned int j = tid; j < bc; j += 1024) {
                const unsigned int key = big[j];
                if (lv == 0 || (key >> (sh + 8)) == prefix) {
                    const unsigned int bin = (key >> sh) & 255u;
                    atomicAdd(&hcnt[bin], 1u);
                    atomicAdd(&hsum[bin], key2f(key));
                }
            }
            __syncthreads();
            if (tid < 256) { s_sc[tid] = hcnt[tid]; s_ss[tid] = hsum[tid]; }
            __syncthreads();
            for (int d = 1; d < 256; d <<= 1) {
                unsigned int uc = 0; float fs = 0.0f;
                if (tid < 256) { uc = (tid + d < 256) ? s_sc[tid + d] : 0u; fs = (tid + d < 256) ? s_ss[tid + d] : 0.0f; }
                __syncthreads();
                if (tid < 256) { s_sc[tid] += uc; s_ss[tid] += fs; }
                __syncthreads();
            }
            if (tid < 256) {
                const unsigned int nxt = (tid < 255) ? s_sc[tid + 1] : 0u;
                const float nxs = (tid < 255) ? s_ss[tid + 1] : 0.0f;
                if (s_sc[tid] >= target && nxt < target) { s_res[0] = (unsigned int)tid; s_res[1] = nxt; s_resf = nxs; }
            }
            __syncthreads();
            prefix = (prefix << 8) | s_res[0];
            target -= s_res[1];        // stays >= 1
            sumab += s_resf;
            __syncthreads();
        }
        s_top = sumab + (float)target * key2f(prefix);   // exact ties
    } else if (k > 0) {
        // ---- FALLBACK: r6 3-level path with global key re-scans ----
        unsigned int* hc = big;
        float* hs = (float*)(big + 4096);
        if (tid < 256) { s_sc[tid] = l1c[b * 256 + tid]; s_ss[tid] = l1s[b * 256 + tid]; }
        __syncthreads();
        for (int d = 1; d < 256; d <<= 1) {
            unsigned int uc = 0; float fs = 0.0f;
            if (tid < 256) { uc = (tid + d < 256) ? s_sc[tid + d] : 0u; fs = (tid + d < 256) ? s_ss[tid + d] : 0.0f; }
            __syncthreads();
            if (tid < 256) { s_sc[tid] += uc; s_ss[tid] += fs; }
            __syncthreads();
        }
        if (tid < 256) {
            const unsigned int nxt = (tid < 255) ? s_sc[tid + 1] : 0u;
            const float nxs = (tid < 255) ? s_ss[tid + 1] : 0.0f;
            if (s_sc[tid] >= k && nxt < k) { s_res[0] = (unsigned int)tid; s_res[1] = nxt; s_resf = nxs; }
        }
        __syncthreads();
        const unsigned int c1 = s_res[0];
        const unsigned int cab1 = s_res[1];
        const float sab1 = s_resf;
        const unsigned int t2 = k - cab1;
        __syncthreads();

        const uint4* kp4 = (const uint4*)(keys + (size_t)b * NA);
        for (int j = tid; j < 4096; j += 1024) { hc[j] = 0u; hs[j] = 0.0f; }
        __syncthreads();
        for (int base = 0; base < NA4; base += 4096) {
            const int j0 = base + tid, j1 = j0 + 1024, j2 = j0 + 2048, j3 = j0 + 3072;
            uint4 v0 = make_uint4(0,0,0,0), v1 = v0, v2 = v0, v3 = v0;
            if (j0 < NA4) v0 = kp4[j0];
            if (j1 < NA4) v1 = kp4[j1];
            if (j2 < NA4) v2 = kp4[j2];
            if (j3 < NA4) v3 = kp4[j3];
            const unsigned int kk[16] = {v0.x,v0.y,v0.z,v0.w, v1.x,v1.y,v1.z,v1.w,
                                         v2.x,v2.y,v2.z,v2.w, v3.x,v3.y,v3.z,v3.w};
#pragma unroll
            for (int j = 0; j < 16; ++j) {
                const unsigned int key = kk[j];
                if (key && (key >> 24) == c1) {
                    const unsigned int bin = (key >> 12) & 0xfffu;
                    atomicAdd(&hc[bin], 1u);
                    atomicAdd(&hs[bin], key2f(key));
                }
            }
        }
        __syncthreads();
        unsigned int c2, cab2; float sab2;
        sel4096_lds(hc, hs, t2, s_sc, s_ss, s_res, &s_resf, &c2, &cab2, &sab2);
        const unsigned int t3 = t2 - cab2;
        const unsigned int top20 = (c1 << 12) | c2;

        for (int j = tid; j < 4096; j += 1024) { hc[j] = 0u; hs[j] = 0.0f; }
        __syncthreads();
        for (int base = 0; base < NA4; base += 4096) {
            const int j0 = base + tid, j1 = j0 + 1024, j2 = j0 + 2048, j3 = j0 + 3072;
            uint4 v0 = make_uint4(0,0,0,0), v1 = v0, v2 = v0, v3 = v0;
            if (j0 < NA4) v0 = kp4[j0];
            if (j1 < NA4) v1 = kp4[j1];
            if (j2 < NA4) v2 = kp4[j2];
            if (j3 < NA4) v3 = kp4[j3];
            const unsigned int kk[16] = {v0.x,v0.y,v0.z,v0.w, v1.x,v1.y,v1.z,v1.w,
                                         v2.x,v2.y,v2.z,v2.w, v3.x,v3.y,v3.z,v3.w};
#pragma unroll
            for (int j = 0; j < 16; ++j) {
                const unsigned int key = kk[j];
                if (key && (key >> 12) == top20) {
                    const unsigned int bin = key & 0xfffu;
                    atomicAdd(&hc[bin], 1u);
                    atomicAdd(&hs[bin], key2f(key));
                }
            }
        }
        __syncthreads();
        unsigned int c3, cab3; float sab3;
        sel4096_lds(hc, hs, t3, s_sc, s_ss, s_res, &s_resf, &c3, &cab3, &sab3);

        const unsigned int keyv = (c1 << 24) | (c2 << 12) | c3;
        const float v = key2f(keyv);
        const unsigned int rem = t3 - cab3;
        s_top = sab1 + sab2 + sab3 + (float)rem * v;
    }

    if (tid == 0) {
        float cls_loss = 0.0f, box_loss = 0.0f;
        if (np > 0) {
            const float* fsc = (const float*)(scal + b * 16);
            const float pos_mean = fsc[2] / (float)np;
            const float neg_mean = s_top / (float)((k > 0) ? k : 1u);
            cls_loss = pos_mean + neg_mean;
            box_loss = fsc[3] / (float)(4u * np);
        }
        out[b] = cls_loss;
        out[NB + b] = box_loss;
    }
}

extern "C" void kernel_launch(void* const* d_in, const int* in_sizes, int n_in,
                              void* d_out, int out_size, void* d_ws, size_t ws_size,
                              hipStream_t stream) {
    const float* cls     = (const float*)d_in[0];   // (B, A, 2)
    const float* reg     = (const float*)d_in[1];   // (B, A, 4)
    const float* anchors = (const float*)d_in[2];   // (1, A, 4)
    const float* ann     = (const float*)d_in[3];   // (B, M, 4)
    unsigned int* ws = (unsigned int*)d_ws;
    unsigned int* scal = ws + O_SCAL;
    unsigned int* l1c  = ws + O_L1C;   float* l1s = (float*)(ws + O_L1S);
    unsigned int* keys = ws + O_KEYS;
    unsigned int* bkt  = ws + O_BKT;
    (void)in_sizes; (void)n_in; (void)out_size; (void)ws_size;

    hipMemsetAsync(d_ws, 0, (size_t)N_ZERO * 4, stream);
    k_main<<<dim3(CPB, NB), 256,  0, stream>>>(cls, reg, anchors, ann, scal, l1c, l1s, keys, bkt);
    k_tail<<<dim3(NB),      1024, 0, stream>>>(keys, scal, l1c, l1s, bkt, (float*)d_out);
}

// Round 8
// 230.533 us; speedup vs baseline: 1.2687x; 1.2687x over previous
//
#include <hip/hip_runtime.h>
#include <stdint.h>

#define NA 200000
#define NB 8
#define NM 64
#define APB 512                 // anchors per k_main block (2 per thread) -- r6 proven config
#define CPB 391                 // 391*512 = 200192 >= 200000
#define NA4 50000               // NA/4 uint4 per image
#define SPB 128                 // scan blocks per image (T1/T3)

// ---- workspace layout (dword offsets) ----
// scal: 8 images x 16 slots: [0]np [1]nn [2]ps(f32) [3]bs(f32) [5]c1 [8]c2 [9]t3 [10]sab12(f32)
#define O_SCAL 0
#define O_L1C  128                   // 8 x 256
#define O_L1S  2176
#define O_L2C  4224                  // 8 x 4096
#define O_L2S  36992
#define O_L3C  69760
#define O_L3S  102528
#define O_KEYS 135296                // 8 x 200000 (byte 541184, 16B-aligned)
#define N_ZERO 135296                // zero scal + L1 + L2 + L3 (541 KB)

__device__ __forceinline__ unsigned int f2key(float f) {
    unsigned int u = __float_as_uint(f);
    return (u & 0x80000000u) ? ~u : (u | 0x80000000u);
}
__device__ __forceinline__ float key2f(unsigned int k) {
    return (k & 0x80000000u) ? __uint_as_float(k & 0x7fffffffu) : __uint_as_float(~k);
}
__device__ __forceinline__ unsigned int calck(const unsigned int* scal, int b) {
    const unsigned int np = scal[b * 16], nn = scal[b * 16 + 1];
    if (!np) return 0u;
    const unsigned int kp = np * 3u;
    return (kp < nn) ? kp : nn;
}

// exact select over 256-bin (cnt,sum) histogram; 256-thread block-collective.
__device__ void sel256(const unsigned int* cnt, const float* sum, unsigned int target,
                       unsigned int* s_sc, float* s_ss, unsigned int* s_res, float* s_resf,
                       unsigned int* c, unsigned int* cab, float* sab) {
    const int t = threadIdx.x;
    s_sc[t] = cnt[t]; s_ss[t] = sum[t];
    __syncthreads();
    for (int d = 1; d < 256; d <<= 1) {      // inclusive suffix scan
        unsigned int uc = (t + d < 256) ? s_sc[t + d] : 0u;
        float fs = (t + d < 256) ? s_ss[t + d] : 0.0f;
        __syncthreads();
        s_sc[t] += uc; s_ss[t] += fs;
        __syncthreads();
    }
    const unsigned int nxt = (t < 255) ? s_sc[t + 1] : 0u;
    const float nxs = (t < 255) ? s_ss[t + 1] : 0.0f;
    if (s_sc[t] >= target && nxt < target) { s_res[0] = (unsigned int)t; s_res[1] = nxt; *s_resf = nxs; }
    __syncthreads();
    *c = s_res[0]; *cab = s_res[1]; *sab = *s_resf;
    __syncthreads();
}

// exact select over 4096-bin global (cnt,sum) histogram; 256-thread block-collective.
__device__ void sel4096g(const unsigned int* cnt, const float* sum, unsigned int target,
                         unsigned int* s_sc, float* s_ss, unsigned int* s_res, float* s_resf,
                         unsigned int* c, unsigned int* cab, float* sab) {
    const int t = threadIdx.x;
    unsigned int cb[16]; float sb[16];
    const uint4*  cp = (const uint4*)(cnt + t * 16);
    const float4* sp = (const float4*)(sum + t * 16);
#pragma unroll
    for (int j = 0; j < 4; ++j) {
        uint4 u = cp[j];  cb[4*j] = u.x; cb[4*j+1] = u.y; cb[4*j+2] = u.z; cb[4*j+3] = u.w;
        float4 f = sp[j]; sb[4*j] = f.x; sb[4*j+1] = f.y; sb[4*j+2] = f.z; sb[4*j+3] = f.w;
    }
    unsigned int cc = 0; float cs = 0.0f;
#pragma unroll
    for (int j = 0; j < 16; ++j) { cc += cb[j]; cs += sb[j]; }
    s_sc[t] = cc; s_ss[t] = cs;
    __syncthreads();
    for (int d = 1; d < 256; d <<= 1) {
        unsigned int uc = (t + d < 256) ? s_sc[t + d] : 0u;
        float fs = (t + d < 256) ? s_ss[t + d] : 0.0f;
        __syncthreads();
        s_sc[t] += uc; s_ss[t] += fs;
        __syncthreads();
    }
    unsigned int run = (t < 255) ? s_sc[t + 1] : 0u;
    float runs = (t < 255) ? s_ss[t + 1] : 0.0f;
#pragma unroll
    for (int j = 15; j >= 0; --j) {
        const unsigned int prev = run; const float prevs = runs;
        run += cb[j]; runs += sb[j];
        if (run >= target && prev < target) {
            s_res[0] = (unsigned int)(t * 16 + j); s_res[1] = prev; *s_resf = prevs;
        }
    }
    __syncthreads();
    *c = s_res[0]; *cab = s_res[1]; *sab = *s_resf;
    __syncthreads();
}

// per-anchor epilogue: key write + LDS L1 hist + pos-path box loss accumulation
__device__ __forceinline__ void epi(
    int b, int i, float4 a4, int arg, bool pos, bool neg,
    const float* __restrict__ cls, const float* __restrict__ reg,
    const float4* sbox, unsigned int* __restrict__ keys,
    unsigned int* hc8, float* hs8, float& posv, float& boxv)
{
    const float2 cv = ((const float2*)cls)[(size_t)b * NA + i];
    unsigned int key = 0u;   // excluded anchors: key 0
    if (neg) {
        const float nl = -cv.y;
        key = f2key(nl);
        atomicAdd(&hc8[key >> 24], 1u);
        atomicAdd(&hs8[key >> 24], nl);
    }
    keys[(size_t)b * NA + i] = key;
    if (pos) {
        posv += -cv.x;
        const float4 g = sbox[arg];
        const float aw = a4.z - a4.x, ah = a4.w - a4.y;
        const float acx = a4.x + 0.5f * aw, acy = a4.y + 0.5f * ah;
        const float gw = g.z - g.x, gh = g.w - g.y;
        const float gcx = g.x + 0.5f * gw, gcy = g.y + 0.5f * gh;
        const float t0 = ((gcx - acx) / (aw + 1e-14f)) / 0.1f;
        const float t1 = ((gcy - acy) / (ah + 1e-14f)) / 0.1f;
        const float t2 = logf(gw / aw) / 0.2f;
        const float t3 = logf(gh / ah) / 0.2f;
        const float4 r = ((const float4*)reg)[(size_t)b * NA + i];
        const float d0 = fabsf(t0 - r.x);
        const float d1 = fabsf(t1 - r.y);
        const float d2 = fabsf(t2 - r.z);
        const float d3 = fabsf(t3 - r.w);
        const float l0 = (d0 < 1.0f) ? 0.5f * d0 * d0 : d0 - 0.5f;
        const float l1 = (d1 < 1.0f) ? 0.5f * d1 * d1 : d1 - 0.5f;
        const float l2 = (d2 < 1.0f) ? 0.5f * d2 * d2 : d2 - 0.5f;
        const float l3 = (d3 < 1.0f) ? 0.5f * d3 * d3 : d3 - 0.5f;
        boxv += l0 + l1 + l2 + l3;
    }
}

// ---------------- K1: r6-exact config (2 anchors/thread, 8-box register stages) ----------------
__global__ __launch_bounds__(256, 4) void k_main(
    const float* __restrict__ cls, const float* __restrict__ reg,
    const float* __restrict__ anchors, const float* __restrict__ ann,
    unsigned int* __restrict__ scal, unsigned int* __restrict__ l1cnt,
    float* __restrict__ l1sum, unsigned int* __restrict__ keys)
{
    __shared__ float4 sbox[NM];
    __shared__ unsigned int hc8[256];
    __shared__ float hs8[256];
    __shared__ unsigned int s_np, s_nn;
    __shared__ float s_ps, s_bs;

    const int b = blockIdx.y;
    const int tid = threadIdx.x;
    if (tid < NM) {
        float4 bb = ((const float4*)ann)[b * NM + tid];
        if (!(bb.x > 0.0f)) {   // invalid -> inter 0, ua inf, ratio 0 (bit-exact vs ref, r3-r7)
            bb.x = __builtin_inff(); bb.y = __builtin_inff();
            bb.z = -__builtin_inff(); bb.w = -__builtin_inff();
        }
        sbox[tid] = bb;
    }
    hc8[tid] = 0u; hs8[tid] = 0.0f;
    if (tid == 0) { s_np = 0u; s_nn = 0u; s_ps = 0.0f; s_bs = 0.0f; }
    __syncthreads();

    const int i0 = blockIdx.x * APB + tid;
    const int i1 = i0 + 256;
    float4 A0 = make_float4(0.f, 0.f, 0.f, 0.f);
    float4 A1 = make_float4(0.f, 0.f, 0.f, 0.f);
    if (i0 < NA) A0 = ((const float4*)anchors)[i0];
    if (i1 < NA) A1 = ((const float4*)anchors)[i1];

    float bi0 = -1.0f, bu0 = 1.0f, bi1 = -1.0f, bu1 = 1.0f;
    int arg0 = 0, arg1 = 0;
    bool pos0, neg0, pos1, neg1;
    {
#pragma clang fp contract(off)
        const float aa0 = (A0.z - A0.x) * (A0.w - A0.y);
        const float aa1 = (A1.z - A1.x) * (A1.w - A1.y);
#pragma unroll 1
        for (int mo = 0; mo < NM; mo += 8) {
            float4 bb[8]; float ab[8];
#pragma unroll
            for (int j = 0; j < 8; ++j) {
                bb[j] = sbox[mo + j];
                ab[j] = (bb[j].z - bb[j].x) * (bb[j].w - bb[j].y);
            }
#pragma unroll
            for (int j = 0; j < 8; ++j) {
                {
                    const float iw = fmaxf(fminf(A0.z, bb[j].z) - fmaxf(A0.x, bb[j].x), 0.0f);
                    const float ih = fmaxf(fminf(A0.w, bb[j].w) - fmaxf(A0.y, bb[j].y), 0.0f);
                    const float inter = iw * ih;
                    const float ua = fmaxf(aa0 + ab[j] - inter, 1e-8f);
                    if (inter * bu0 > bi0 * ua) { bi0 = inter; bu0 = ua; arg0 = mo + j; }
                }
                {
                    const float iw = fmaxf(fminf(A1.z, bb[j].z) - fmaxf(A1.x, bb[j].x), 0.0f);
                    const float ih = fmaxf(fminf(A1.w, bb[j].w) - fmaxf(A1.y, bb[j].y), 0.0f);
                    const float inter = iw * ih;
                    const float ua = fmaxf(aa1 + ab[j] - inter, 1e-8f);
                    if (inter * bu1 > bi1 * ua) { bi1 = inter; bu1 = ua; arg1 = mo + j; }
                }
            }
        }
        pos0 = (bi0 >= 0.5f * bu0); neg0 = (bi0 < 0.3f * bu0);
        pos1 = (bi1 >= 0.5f * bu1); neg1 = (bi1 < 0.3f * bu1);
    }

    float posv = 0.0f, boxv = 0.0f;
    if (i0 < NA) epi(b, i0, A0, arg0, pos0, neg0, cls, reg, (const float4*)sbox, keys, hc8, hs8, posv, boxv);
    else { pos0 = false; neg0 = false; }
    if (i1 < NA) epi(b, i1, A1, arg1, pos1, neg1, cls, reg, (const float4*)sbox, keys, hc8, hs8, posv, boxv);
    else { pos1 = false; neg1 = false; }

    const unsigned long long pb0 = __ballot(pos0);
    const unsigned long long pb1 = __ballot(pos1);
    const unsigned long long nb0 = __ballot(neg0);
    const unsigned long long nb1 = __ballot(neg1);
    if (pb0 | pb1) {
        for (int off = 32; off; off >>= 1) {
            posv += __shfl_xor(posv, off);
            boxv += __shfl_xor(boxv, off);
        }
    }
    if ((tid & 63) == 0) {
        const unsigned int nc = (unsigned int)(__popcll(nb0) + __popcll(nb1));
        const unsigned int pc = (unsigned int)(__popcll(pb0) + __popcll(pb1));
        if (nc) atomicAdd(&s_nn, nc);
        if (pc) { atomicAdd(&s_np, pc); atomicAdd(&s_ps, posv); atomicAdd(&s_bs, boxv); }
    }
    __syncthreads();
    unsigned int* sg = scal + b * 16;
    if (tid == 0) {
        if (s_nn) atomicAdd(&sg[1], s_nn);
        if (s_np) {
            atomicAdd(&sg[0], s_np);
            atomicAdd((float*)(sg + 2), s_ps);
            atomicAdd((float*)(sg + 3), s_bs);
        }
    }
    if (hc8[tid]) {
        atomicAdd(&l1cnt[b * 256 + tid], hc8[tid]);
        atomicAdd(&l1sum[b * 256 + tid], hs8[tid]);
    }
}

// ---------------- T1: parallel L2 hist (128 blocks/image, c1 recomputed per block) ----------
__global__ __launch_bounds__(256) void k_h2(
    const unsigned int* __restrict__ keys, const unsigned int* __restrict__ scal,
    const unsigned int* __restrict__ l1c, const float* __restrict__ l1s,
    unsigned int* __restrict__ l2c, float* __restrict__ l2s)
{
    __shared__ unsigned int s_sc[256]; __shared__ float s_ss[256];
    __shared__ unsigned int s_res[2];  __shared__ float s_resf;
    const int b = blockIdx.x >> 7;
    const int sub = blockIdx.x & (SPB - 1);
    const int tid = threadIdx.x;
    const unsigned int k = calck(scal, b);
    if (k == 0) return;   // block-uniform
    unsigned int c1, cab1; float sab1;
    sel256(l1c + b * 256, l1s + b * 256, k, s_sc, s_ss, s_res, &s_resf, &c1, &cab1, &sab1);

    const uint4* kp4 = (const uint4*)(keys + (size_t)b * NA);
    const int j0 = sub * 256 + tid;          // < 32768 < NA4, always valid
    const int j1 = j0 + SPB * 256;
    const uint4 v0 = kp4[j0];
    const uint4 v1 = (j1 < NA4) ? kp4[j1] : make_uint4(0, 0, 0, 0);
    const unsigned int kk[8] = {v0.x, v0.y, v0.z, v0.w, v1.x, v1.y, v1.z, v1.w};
#pragma unroll
    for (int j = 0; j < 8; ++j) {
        const unsigned int key = kk[j];
        if (key && (key >> 24) == c1) {
            const unsigned int bin = (key >> 12) & 0xfffu;
            atomicAdd(&l2c[b * 4096 + bin], 1u);
            atomicAdd(&l2s[b * 4096 + bin], key2f(key));
        }
    }
}

// ---------------- T2: level-2 select, persist chain state (8 blocks) ----------------
__global__ __launch_bounds__(256) void k_s2(
    unsigned int* __restrict__ scal,
    const unsigned int* __restrict__ l1c, const float* __restrict__ l1s,
    const unsigned int* __restrict__ l2c, const float* __restrict__ l2s)
{
    __shared__ unsigned int s_sc[256]; __shared__ float s_ss[256];
    __shared__ unsigned int s_res[2];  __shared__ float s_resf;
    const int b = blockIdx.x;
    const unsigned int k = calck(scal, b);
    if (k == 0) return;
    unsigned int c1, cab1; float sab1;
    sel256(l1c + b * 256, l1s + b * 256, k, s_sc, s_ss, s_res, &s_resf, &c1, &cab1, &sab1);
    const unsigned int t2 = k - cab1;
    unsigned int c2, cab2; float sab2;
    sel4096g(l2c + b * 4096, l2s + b * 4096, t2, s_sc, s_ss, s_res, &s_resf, &c2, &cab2, &sab2);
    if (threadIdx.x == 0) {
        unsigned int* s = scal + b * 16;
        s[5] = c1; s[8] = c2; s[9] = t2 - cab2;
        ((float*)s)[10] = sab1 + sab2;
    }
}

// ---------------- T3: parallel L3 hist (128 blocks/image, prefix from scal) ----------------
__global__ __launch_bounds__(256) void k_h3(
    const unsigned int* __restrict__ keys, const unsigned int* __restrict__ scal,
    unsigned int* __restrict__ l3c, float* __restrict__ l3s)
{
    const int b = blockIdx.x >> 7;
    const int sub = blockIdx.x & (SPB - 1);
    const int tid = threadIdx.x;
    const unsigned int k = calck(scal, b);
    if (k == 0) return;   // block-uniform
    const unsigned int top20 = (scal[b * 16 + 5] << 12) | scal[b * 16 + 8];

    const uint4* kp4 = (const uint4*)(keys + (size_t)b * NA);
    const int j0 = sub * 256 + tid;
    const int j1 = j0 + SPB * 256;
    const uint4 v0 = kp4[j0];
    const uint4 v1 = (j1 < NA4) ? kp4[j1] : make_uint4(0, 0, 0, 0);
    const unsigned int kk[8] = {v0.x, v0.y, v0.z, v0.w, v1.x, v1.y, v1.z, v1.w};
#pragma unroll
    for (int j = 0; j < 8; ++j) {
        const unsigned int key = kk[j];
        if (key && (key >> 12) == top20) {
            const unsigned int bin = key & 0xfffu;
            atomicAdd(&l3c[b * 4096 + bin], 1u);
            atomicAdd(&l3s[b * 4096 + bin], key2f(key));
        }
    }
}

// ---------------- T4: level-3 select + finalize (8 blocks) ----------------
__global__ __launch_bounds__(256) void k_fin(
    const unsigned int* __restrict__ scal,
    const unsigned int* __restrict__ l3c, const float* __restrict__ l3s,
    float* __restrict__ out)
{
    __shared__ unsigned int s_sc[256]; __shared__ float s_ss[256];
    __shared__ unsigned int s_res[2];  __shared__ float s_resf;
    const int b = blockIdx.x;
    const unsigned int np = scal[b * 16];
    const unsigned int k = calck(scal, b);
    float s_top = 0.0f;
    if (k > 0) {   // block-uniform
        const unsigned int t3 = scal[b * 16 + 9];
        unsigned int c3, cab3; float sab3;
        sel4096g(l3c + b * 4096, l3s + b * 4096, t3, s_sc, s_ss, s_res, &s_resf, &c3, &cab3, &sab3);
        const unsigned int keyv = (scal[b * 16 + 5] << 24) | (scal[b * 16 + 8] << 12) | c3;
        const float v = key2f(keyv);
        const unsigned int rem = t3 - cab3;      // exact tie handling: leaf keys identical
        s_top = ((const float*)(scal + b * 16))[10] + sab3 + (float)rem * v;
    }
    if (threadIdx.x == 0) {
        float cls_loss = 0.0f, box_loss = 0.0f;
        if (np > 0) {
            const float* fsc = (const float*)(scal + b * 16);
            const float pos_mean = fsc[2] / (float)np;
            const float neg_mean = s_top / (float)((k > 0) ? k : 1u);
            cls_loss = pos_mean + neg_mean;
            box_loss = fsc[3] / (float)(4u * np);
        }
        out[b] = cls_loss;
        out[NB + b] = box_loss;
    }
}

extern "C" void kernel_launch(void* const* d_in, const int* in_sizes, int n_in,
                              void* d_out, int out_size, void* d_ws, size_t ws_size,
                              hipStream_t stream) {
    const float* cls     = (const float*)d_in[0];   // (B, A, 2)
    const float* reg     = (const float*)d_in[1];   // (B, A, 4)
    const float* anchors = (const float*)d_in[2];   // (1, A, 4)
    const float* ann     = (const float*)d_in[3];   // (B, M, 4)
    unsigned int* ws = (unsigned int*)d_ws;
    unsigned int* scal = ws + O_SCAL;
    unsigned int* l1c  = ws + O_L1C;   float* l1s = (float*)(ws + O_L1S);
    unsigned int* l2c  = ws + O_L2C;   float* l2s = (float*)(ws + O_L2S);
    unsigned int* l3c  = ws + O_L3C;   float* l3s = (float*)(ws + O_L3S);
    unsigned int* keys = ws + O_KEYS;
    (void)in_sizes; (void)n_in; (void)out_size; (void)ws_size;

    hipMemsetAsync(d_ws, 0, (size_t)N_ZERO * 4, stream);
    k_main<<<dim3(CPB, NB), 256, 0, stream>>>(cls, reg, anchors, ann, scal, l1c, l1s, keys);
    k_h2  <<<dim3(NB * SPB), 256, 0, stream>>>(keys, scal, l1c, l1s, l2c, l2s);
    k_s2  <<<dim3(NB),       256, 0, stream>>>(scal, l1c, l1s, l2c, l2s);
    k_h3  <<<dim3(NB * SPB), 256, 0, stream>>>(keys, scal, l3c, l3s);
    k_fin <<<dim3(NB),       256, 0, stream>>>(scal, l3c, l3s, (float*)d_out);
}